// Round 6
// baseline (210.257 us; speedup 1.0000x reference)
//
#include <hip/hip_runtime.h>
#include <stdint.h>

#define N_Q 16384
#define M_P 1024
#define D_K 1024

typedef __attribute__((ext_vector_type(8))) __bf16 bf16x8;
typedef __attribute__((ext_vector_type(4))) float floatx4;
typedef __attribute__((ext_vector_type(16))) float floatx16;
typedef __attribute__((ext_vector_type(4))) unsigned int uint4v;

#define AS1 __attribute__((address_space(1)))
#define AS3 __attribute__((address_space(3)))

__device__ __forceinline__ unsigned short f2bf(float f) {
    unsigned int u = __float_as_uint(f);
    u += 0x7fffu + ((u >> 16) & 1u);   // round-to-nearest-even
    return (unsigned short)(u >> 16);
}
__device__ __forceinline__ float bf2f(unsigned short h) {
    return __uint_as_float(((unsigned int)h) << 16);
}

// Split 8 fp32 (one k-chunk) -> packed bf16 hi (16B) + lo (16B).
__device__ __forceinline__ void split_chunk(floatx4 f0, floatx4 f1,
                                            uint4v* hi, uint4v* lo) {
    float e[8] = {f0.x, f0.y, f0.z, f0.w, f1.x, f1.y, f1.z, f1.w};
    unsigned int hb[4], lb[4];
#pragma unroll
    for (int p = 0; p < 4; ++p) {
        unsigned int u0 = __float_as_uint(e[2 * p]);
        unsigned int u1 = __float_as_uint(e[2 * p + 1]);
        hb[p] = __builtin_amdgcn_perm(u1, u0, 0x07060302);  // [u0>>16, u1>>16]
        float l0 = e[2 * p]     - __uint_as_float(u0 & 0xffff0000u);
        float l1 = e[2 * p + 1] - __uint_as_float(u1 & 0xffff0000u);
        lb[p] = __builtin_amdgcn_perm(__float_as_uint(l1), __float_as_uint(l0),
                                      0x07060302);
    }
    uint4v h = {hb[0], hb[1], hb[2], hb[3]};
    uint4v l = {lb[0], lb[1], lb[2], lb[3]};
    *hi = h;
    *lo = l;
}

// ---------------------------------------------------------------------------
// Proto convert: split fp32 -> bf16 hi/lo + p2[m]. One block per row. ~5 us.
// ---------------------------------------------------------------------------
__global__ __launch_bounds__(256) void convert_proto_kernel(
    const float* __restrict__ proto, unsigned short* __restrict__ ph,
    unsigned short* __restrict__ pl, float* __restrict__ p2) {
    __shared__ float sred[4];
    int m = blockIdx.x;
    int t = threadIdx.x;
    size_t base4 = (size_t)m * (D_K / 4) + t;
    float4 v = ((const float4*)proto)[base4];
    ushort4 h, l;
    h.x = f2bf(v.x); l.x = f2bf(v.x - bf2f(h.x));
    h.y = f2bf(v.y); l.y = f2bf(v.y - bf2f(h.y));
    h.z = f2bf(v.z); l.z = f2bf(v.z - bf2f(h.z));
    h.w = f2bf(v.w); l.w = f2bf(v.w - bf2f(h.w));
    ((ushort4*)ph)[base4] = h;
    ((ushort4*)pl)[base4] = l;
    float sq = v.x * v.x + v.y * v.y + v.z * v.z + v.w * v.w;
#pragma unroll
    for (int off = 1; off < 64; off <<= 1) sq += __shfl_xor(sq, off);
    if ((t & 63) == 0) sred[t >> 6] = sq;
    __syncthreads();
    if (t == 0) p2[m] = sred[0] + sred[1] + sred[2] + sred[3];
}

// ---------------------------------------------------------------------------
// GEMM: logits[n,m] = 2*sum_d q[n,d]*p[m,d] - p2[m], bf16 hi/lo 3-term.
//
// R15: RESTRUCTURAL -- MFMA shape 16x16x32 -> 32x32x16.
// R14 post-mortem (steady 95.0 == R13's 95.6, delta 0%): schedule family
// exhausted per pre-commitment; 160KB LDS also caused a 194us cold dispatch
// (1 block/CU needs a FULLY empty CU) -> LDS reverted to 128KB / R13 cfg.
// Why the shape swap: measured ceilings 32x32 = 2382-2495 TF vs 16x16 =
// 2075-2176 (m06/m119): +10-15% pipe throughput at identical FLOPs, and
// halves MFMA instruction count (96->48/wave/step).
// What is UNCHANGED: LDS images, staging, granule swizzle (placement
// bijection is shape-independent), split numerics, R13 schedule skeleton
// (counted-lgkm read-ahead, one barrier/step, vmcnt(4) discipline).
// What changes: fragment lane mapping (A row=lane&31, k0=(lane>>5)*8 --
// exact analog of the 16x16 mapping this kernel already proves), MFMA
// calls, epilogue C/D layout (HW-verified m74/m101: col=lane&31,
// row=(reg&3)+8*(reg>>2)+4*(lane>>5)).
// Per step: 4 clusters of 12 MFMA (tpair x khalf); reads per phase: 4
// ds_read_b128 (2 row-tiles x hi/lo), counted lgkm(4) waits as R13.
// ---------------------------------------------------------------------------
__global__ __launch_bounds__(512, 2) void gemm_logits_kernel(
    const float* __restrict__ query,
    const unsigned short* __restrict__ ph, const unsigned short* __restrict__ pl,
    const float* __restrict__ p2, float* __restrict__ out) {
    __shared__ unsigned short sAh[2][16 * 512];   // 2 x 16 KB
    __shared__ unsigned short sAl[2][16 * 512];   // 2 x 16 KB
    __shared__ unsigned short sBh[2][16 * 512];   // 2 x 16 KB
    __shared__ unsigned short sBl[2][16 * 512];   // 2 x 16 KB  (128 KB)

    const int tid = threadIdx.x;
    const int wave = tid >> 6;   // 0..7
    const int lane = tid & 63;
    const int wr = wave >> 2;    // 0..1: row half (128 rows)
    const int wc = wave & 3;     // 0..3: col quarter (64 cols)

    // XCD-aware: 8 chunks of 32 blocks; chunk = same col-tile, 32 row-tiles.
    const int b = blockIdx.x;            // 0..255
    const int v = (b & 7) * 32 + (b >> 3);
    const int colt = v >> 6;             // 0..3
    const int rowt = v & 63;             // 0..63
    const int row0 = rowt * 256;
    const int col0 = colt * 256;

    // B staging (R4-verified pre-swizzled source, linear gload_lds dest):
    const int rlB = lane >> 2;
    const int cioB = (lane & 3) ^ ((lane >> 3) & 3);
    const int halfB = wave >> 2;         // 0: hi, 1: lo
    const int sgB = wave & 3;
    const unsigned short* gB = (halfB ? pl : ph)
        + (size_t)(col0 + sgB * 64 + rlB) * D_K + cioB * 8;

    // A staging: wave covers rows wave*32..wave*32+31 (2 subtiles of 16).
    const int rlA = lane >> 2;          // 0..15
    const int cA = lane & 3;            // k-granule 0..3
    const AS1 float* gA = (const AS1 float*)query
        + (size_t)(row0 + wave * 32 + rlA) * D_K + cA * 8;
    const int wroff = (4 * rlA + (cA ^ ((rlA >> 1) & 3))) * 8;  // shorts

    // 32x32x16 fragment addressing: lane covers row/col r32 = lane&31,
    // 8 contiguous k at granule g = kh*2 + (lane>>5). Same placement
    // swizzle as staging: pos = 4*rl + (g ^ ((rl>>1)&3)).
    const int r32 = lane & 31;
    const int rl16 = lane & 15;          // row within 16-row subtile
    const int subsel = (lane & 31) >> 4; // which 16-row subtile of the 32
    const int ghalf = lane >> 5;         // k-granule low bit source

    floatx16 acc[4][2];                  // [row-tile ti][col-tile tj]
#pragma unroll
    for (int i = 0; i < 4; ++i)
#pragma unroll
        for (int j = 0; j < 2; ++j)
#pragma unroll
            for (int r = 0; r < 16; ++r) acc[i][j][r] = 0.0f;

    floatx4 f0[2], f1[2];        // A prefetch regs (16 VGPR)
    bf16x8 bh[2][2], bl[2][2];   // B fragments [tj][kh] (held one K-step)
    bf16x8 ah[2][2], al[2][2];   // A fragments [set][u], 2 reg-sets

    auto issueA = [&](int kb) {
#pragma unroll
        for (int s = 0; s < 2; ++s) {
            const AS1 float* p = gA + (size_t)(s * 16) * D_K + kb;
            f0[s] = *(const AS1 floatx4*)p;
            f1[s] = *(const AS1 floatx4*)(p + 4);
        }
    };
    auto issueB = [&](int kb, int nxt) {
        unsigned short* dstB = (halfB ? sBl[nxt] : sBh[nxt]) + sgB * 4 * 512;
#pragma unroll
        for (int s = 0; s < 4; ++s)
            __builtin_amdgcn_global_load_lds(
                (const AS1 unsigned int*)(const void*)(gB + (size_t)(s * 16) * D_K + kb),
                (AS3 unsigned int*)(void*)(dstB + s * 512), 16, 0, 0);
    };
    auto writeA = [&](int nxt, int s) {
        uint4v hi, lo;
        split_chunk(f0[s], f1[s], &hi, &lo);
        const int off = (wave * 2 + s) * 512 + wroff;
        *(uint4v*)(sAh[nxt] + off) = hi;
        *(uint4v*)(sAl[nxt] + off) = lo;
    };
    // fragment byte offset within a 32-row/col tile starting at subtile s0
    auto fragoff32 = [&](int s0, int kh) {
        const int g = kh * 2 + ghalf;
        return (s0 + subsel) * 512 + (4 * rl16 + (g ^ ((rl16 >> 1) & 3))) * 8;
    };
    auto ldBfrag = [&](int cur) {
#pragma unroll
        for (int tj = 0; tj < 2; ++tj)
#pragma unroll
            for (int kh = 0; kh < 2; ++kh) {
                const int off = fragoff32(wc * 4 + tj * 2, kh);
                bh[tj][kh] = *(const bf16x8*)(sBh[cur] + off);
                bl[tj][kh] = *(const bf16x8*)(sBl[cur] + off);
            }
    };
    // load A frags for row-tile pair tp (tiles tp*2, tp*2+1), k-half kh
    auto ldA = [&](int cur, int tp, int kh, int set) {
#pragma unroll
        for (int u = 0; u < 2; ++u) {
            const int ti = tp * 2 + u;
            const int off = fragoff32(wr * 8 + ti * 2, kh);
            ah[set][u] = *(const bf16x8*)(sAh[cur] + off);
            al[set][u] = *(const bf16x8*)(sAl[cur] + off);
        }
    };
    // one cluster: row-tile pair tp x 2 col-tiles x 3 terms = 12 MFMA
    auto mfmaC = [&](int tp, int kh, int set) {
#pragma unroll
        for (int tj = 0; tj < 2; ++tj)
#pragma unroll
            for (int u = 0; u < 2; ++u) {
                const int ti = tp * 2 + u;
                acc[ti][tj] = __builtin_amdgcn_mfma_f32_32x32x16_bf16(ah[set][u], bh[tj][kh], acc[ti][tj], 0, 0, 0);
                acc[ti][tj] = __builtin_amdgcn_mfma_f32_32x32x16_bf16(ah[set][u], bl[tj][kh], acc[ti][tj], 0, 0, 0);
                acc[ti][tj] = __builtin_amdgcn_mfma_f32_32x32x16_bf16(al[set][u], bh[tj][kh], acc[ti][tj], 0, 0, 0);
            }
    };

#define LGKM_MFMA(n, tp, kh, set)                               \
    asm volatile("s_waitcnt lgkmcnt(" #n ")" ::: "memory");     \
    __builtin_amdgcn_sched_barrier(0);                          \
    __builtin_amdgcn_s_setprio(1);                              \
    mfmaC(tp, kh, set);                                         \
    __builtin_amdgcn_s_setprio(0);

    // One K-step t (R13 skeleton). DS order: [B 8r][A(tp0,kh0) 4r]
    // [A(tp1,kh0) 4r] |4| [A(tp0,kh1) 4r] |4| [A(tp1,kh1) 4r] |4|
    // [W 4w] lgkm(4) | final cluster | lgkm(0).
    // Vmem order: [B(t+1) x4][A(t+2) x4]; end-of-step vmcnt(4).
    auto stepf = [&](int kbB, int kbA, int cur, int nxt, bool pfB, bool pfA) {
        if (pfB) issueB(kbB, nxt);
        ldBfrag(cur);                // 8 reads
        ldA(cur, 0, 0, 0);           // 4 reads
        ldA(cur, 1, 0, 1);           // 4 reads   [16 outstanding]
        LGKM_MFMA(4, 0, 0, 0)        // B+set0 done; set1 in flight
        ldA(cur, 0, 1, 0);
        LGKM_MFMA(4, 1, 0, 1)        // (tp1,kh0) done; (tp0,kh1) in flight
        ldA(cur, 1, 1, 1);
        LGKM_MFMA(4, 0, 1, 0)        // (tp0,kh1) done; (tp1,kh1) in flight
        if (pfB) { writeA(nxt, 0); writeA(nxt, 1); }  // VALU + 4 ds_write
        if (pfA) issueA(kbA);        // f-regs free after split VALU
        if (pfB) { asm volatile("s_waitcnt lgkmcnt(4)" ::: "memory"); }
        else     { asm volatile("s_waitcnt lgkmcnt(0)" ::: "memory"); }
        __builtin_amdgcn_sched_barrier(0);
        __builtin_amdgcn_s_setprio(1);
        mfmaC(1, 1, 1);
        __builtin_amdgcn_s_setprio(0);
        asm volatile("s_waitcnt lgkmcnt(0)" ::: "memory");  // ds_writes drained
        if (pfB) {
            if (pfA) { asm volatile("s_waitcnt vmcnt(4)" ::: "memory"); }
            else     { asm volatile("s_waitcnt vmcnt(0)" ::: "memory"); }
        }
        __builtin_amdgcn_s_barrier();   // the ONE barrier per step
    };

    // prologue: tile 0 -> buf0; prefetch A(t1).
    issueA(0);                  // A(t0): oldest 4 vmem
    issueB(0, 0);               // B(t0): next 4
    writeA(0, 0);               // compiler waits vmcnt(4): A(t0) done, B in flight
    writeA(0, 1);
    issueA(32);                 // A(t1) in flight across the barrier
    asm volatile("s_waitcnt lgkmcnt(0)" ::: "memory");
    asm volatile("s_waitcnt vmcnt(4)" ::: "memory");   // B(t0) landed
    __builtin_amdgcn_s_barrier();

    for (int kt = 0; kt < 30; kt += 2) {
        stepf((kt + 1) * 32, (kt + 2) * 32, 0, 1, true, true);
        stepf((kt + 2) * 32, (kt + 3) * 32, 1, 0, true, true);
    }
    stepf(31 * 32, 0, 0, 1, true, false);   // t=30: stage t31, drain vmcnt(0)
    stepf(0, 0, 1, 0, false, false);        // t=31: compute only

#undef LGKM_MFMA

    // ---- epilogue: logits = 2*qp - p2[col] ----
    // 32x32 C/D layout (HW-verified m74/m101):
    // col = lane&31, row = (reg&3) + 8*(reg>>2) + 4*(lane>>5)
#pragma unroll
    for (int tj = 0; tj < 2; ++tj) {
        const int gc = col0 + wc * 64 + tj * 32 + r32;
        const float p2v = p2[gc];
#pragma unroll
        for (int ti = 0; ti < 4; ++ti) {
            const int rbase = row0 + wr * 128 + ti * 32 + 4 * ghalf;
#pragma unroll
            for (int reg = 0; reg < 16; ++reg) {
                const int gr = rbase + (reg & 3) + 8 * (reg >> 2);
                out[(size_t)gr * M_P + gc] = 2.0f * acc[ti][tj][reg] - p2v;
            }
        }
    }
}

// ---------------------------------------------------------------------------
// Fallback (tiny workspace): naive fp32 logits + separate softmax.
// ---------------------------------------------------------------------------
__global__ __launch_bounds__(256) void naive_logits_kernel(
    const float* __restrict__ query, const float* __restrict__ proto,
    float* __restrict__ out) {
    __shared__ float qs[D_K];
    int n = blockIdx.x;
    int t = threadIdx.x;
    ((float4*)qs)[t] = ((const float4*)(query + (size_t)n * D_K))[t];
    __syncthreads();
    float acc[4] = {0.f, 0.f, 0.f, 0.f};
    float pp[4] = {0.f, 0.f, 0.f, 0.f};
    for (int d = 0; d < D_K; d += 4) {
        float4 qv = *(const float4*)(qs + d);
#pragma unroll
        for (int j = 0; j < 4; ++j) {
            const float4 pv = *(const float4*)(proto + (size_t)(t + 256 * j) * D_K + d);
            acc[j] += qv.x * pv.x + qv.y * pv.y + qv.z * pv.z + qv.w * pv.w;
            pp[j] += pv.x * pv.x + pv.y * pv.y + pv.z * pv.z + pv.w * pv.w;
        }
    }
#pragma unroll
    for (int j = 0; j < 4; ++j)
        out[(size_t)n * M_P + t + 256 * j] = 2.0f * acc[j] - pp[j];
}

// ---------------------------------------------------------------------------
// In-place row softmax, wave-per-row (no LDS/barriers). ~24 us measured.
// ---------------------------------------------------------------------------
__global__ __launch_bounds__(256) void softmax_kernel(float* __restrict__ out) {
    const int lane = threadIdx.x & 63;
    int n = blockIdx.x * 4 + (threadIdx.x >> 6);
    for (int it = 0; it < 2; ++it, n += 8192) {
        float* row = out + (size_t)n * M_P;
        floatx4 v[4];
#pragma unroll
        for (int k = 0; k < 4; ++k)
            v[k] = *((const floatx4*)row + k * 64 + lane);
        float mx = fmaxf(fmaxf(v[0].x, v[0].y), fmaxf(v[0].z, v[0].w));
#pragma unroll
        for (int k = 1; k < 4; ++k)
            mx = fmaxf(mx, fmaxf(fmaxf(v[k].x, v[k].y), fmaxf(v[k].z, v[k].w)));
#pragma unroll
        for (int off = 1; off < 64; off <<= 1) mx = fmaxf(mx, __shfl_xor(mx, off));
        float s = 0.0f;
#pragma unroll
        for (int k = 0; k < 4; ++k) {
            v[k].x = __expf(v[k].x - mx);
            v[k].y = __expf(v[k].y - mx);
            v[k].z = __expf(v[k].z - mx);
            v[k].w = __expf(v[k].w - mx);
            s += v[k].x + v[k].y + v[k].z + v[k].w;
        }
#pragma unroll
        for (int off = 1; off < 64; off <<= 1) s += __shfl_xor(s, off);
        const float inv = 1.0f / s;
#pragma unroll
        for (int k = 0; k < 4; ++k) {
            floatx4 o;
            o.x = v[k].x * inv; o.y = v[k].y * inv;
            o.z = v[k].z * inv; o.w = v[k].w * inv;
            __builtin_nontemporal_store(o, (floatx4*)row + k * 64 + lane);
        }
    }
}

extern "C" void kernel_launch(void* const* d_in, const int* in_sizes, int n_in,
                              void* d_out, int out_size, void* d_ws, size_t ws_size,
                              hipStream_t stream) {
    const float* query = (const float*)d_in[0];
    const float* proto = (const float*)d_in[1];
    float* out = (float*)d_out;

    const size_t pElems = (size_t)M_P * D_K;   // 1M
    const size_t needed = pElems * 2 * 2 + M_P * 4;  // ~4.2 MiB

    if (ws_size >= needed) {
        unsigned short* ph = (unsigned short*)d_ws;
        unsigned short* pl = ph + pElems;
        float* p2 = (float*)(pl + pElems);

        convert_proto_kernel<<<M_P, 256, 0, stream>>>(proto, ph, pl, p2);
        gemm_logits_kernel<<<(N_Q / 256) * (M_P / 256), 512, 0, stream>>>(
            query, ph, pl, p2, out);
    } else {
        naive_logits_kernel<<<N_Q, 256, 0, stream>>>(query, proto, out);
    }
    softmax_kernel<<<2048, 256, 0, stream>>>(out);
}